// Round 16
// baseline (312.358 us; speedup 1.0000x reference)
//
#include <hip/hip_runtime.h>
#include <hip/hip_bf16.h>

// B=2, L=2048, hidden=2048, H=16, KV=4, D=128, WIN=512
// Pipeline (5 dispatches):
//   1) fused cast x, Wq|Wk|Wv, Wo -> bf16
//   2) gemm_qkv: qkv = x @ Wqkv^T, FUSED RMSNorm+RoPE epilogue for q/k heads
//      (slim: no reg arrays, inline Rs reduce, rsqrt recompute);
//      v heads -> coalesced rows in vbuf[2][2048][512]
//   3) transpose_v: vbuf -> vt[2,4,128,2048] (LDS transpose, coalesced)
//   4) sliding-window flash attention (GQA-merged, XCD-pinned, S^T dataflow)
//   5) out = attn @ Wo^T (fp32 out)

typedef unsigned short u16;
typedef unsigned int u32;
typedef __attribute__((ext_vector_type(8))) short bf16x8;
typedef __attribute__((ext_vector_type(4))) float f32x4;

#define AS1 __attribute__((address_space(1)))
#define AS3 __attribute__((address_space(3)))

__device__ __forceinline__ u16 f2b(float f) {
  union { float f; u32 u; } c; c.f = f;
  return (u16)((c.u + 0x8000u) >> 16);   // fast round; inputs bounded, no NaN/inf
}
__device__ __forceinline__ float b2f(u16 u) {
  union { u32 u; float f; } c; c.u = ((u32)u) << 16; return c.f;
}

// ---------------- fused fp32 -> bf16 casts ----------------
__global__ __launch_bounds__(256) void cvt_all(const float* __restrict__ x,
                                               const float* __restrict__ wq,
                                               const float* __restrict__ wk,
                                               const float* __restrict__ wv,
                                               const float* __restrict__ wo,
                                               u16* __restrict__ xb,
                                               u16* __restrict__ wqkvb,
                                               u16* __restrict__ wob) {
  int blk = blockIdx.x;
  const float* s; u16* d; int off;
  if (blk < 8192)       { s = x;  d = xb;              off = blk * 1024; }
  else if (blk < 12288) { s = wq; d = wqkvb;           off = (blk - 8192) * 1024; }
  else if (blk < 13312) { s = wk; d = wqkvb + 4194304; off = (blk - 12288) * 1024; }
  else if (blk < 14336) { s = wv; d = wqkvb + 5242880; off = (blk - 13312) * 1024; }
  else                  { s = wo; d = wob;             off = (blk - 14336) * 1024; }
  int i = off + threadIdx.x * 4;
  float4 v = *(const float4*)(s + i);
  ushort4 o;
  o.x = f2b(v.x); o.y = f2b(v.y); o.z = f2b(v.z); o.w = f2b(v.w);
  *(ushort4*)(d + i) = o;
}

// ---- gemm_qkv: C = x @ Wqkv^T with fused RMSNorm+RoPE (q/k) ---------------
// 128x128 tile, BK=64, 4 waves (2x2). Wave B-cols permuted so RoPE pairs
// (d, d+64) are register-local: col(j) = wn*32 + (j&1)*16 + (j>>1)*64 + l16.
// V heads write coalesced rows to vbuf[b][l][512] (transposed separately).
__global__ __launch_bounds__(256) void gemm_qkv(const u16* __restrict__ A,
                                                const u16* __restrict__ Bm,
                                                const float* __restrict__ cosT,
                                                const float* __restrict__ sinT,
                                                const float* __restrict__ qw,
                                                const float* __restrict__ kw,
                                                u16* __restrict__ qo,
                                                u16* __restrict__ ko,
                                                u16* __restrict__ vb) {
  constexpr int K = 2048;
  __shared__ u16 As[128][64];
  __shared__ u16 Bs[128][64];
  __shared__ float Rs[2][2][64];
  const int tid  = threadIdx.x;
  const int w    = tid >> 6, lane = tid & 63, quad = lane >> 4, l16 = lane & 15;
  const int wm   = w >> 1, wn = w & 1;
  const int m0   = blockIdx.y * 128;
  const int hh   = blockIdx.x;              // head-block: 0-15 q, 16-19 k, 20-23 v

  f32x4 zero = {0.f, 0.f, 0.f, 0.f};
  f32x4 acc[4][4];
#pragma unroll
  for (int i = 0; i < 4; i++)
#pragma unroll
    for (int j = 0; j < 4; j++) acc[i][j] = zero;

  const int srow = lane >> 3;
  const int swz8 = ((lane & 7) ^ (lane >> 3)) * 8;
  const int n0   = hh * 128;

  for (int k0 = 0; k0 < K; k0 += 64) {
#pragma unroll
    for (int p = 0; p < 4; ++p) {
      int row = p * 32 + w * 8 + srow;
      __builtin_amdgcn_global_load_lds(
          (const AS1 void*)(A + (size_t)(m0 + row) * K + k0 + swz8),
          (AS3 void*)((char*)&As[0][0] + p * 4096 + w * 1024), 16, 0, 0);
      __builtin_amdgcn_global_load_lds(
          (const AS1 void*)(Bm + (size_t)(n0 + row) * K + k0 + swz8),
          (AS3 void*)((char*)&Bs[0][0] + p * 4096 + w * 1024), 16, 0, 0);
    }
    __syncthreads();
#pragma unroll
    for (int kk = 0; kk < 64; kk += 32) {
      const int cs = ((kk >> 3) + quad) ^ (l16 & 7);
      bf16x8 af[4], bfr[4];
#pragma unroll
      for (int i = 0; i < 4; i++)
        af[i] = *(const bf16x8*)((const char*)&As[0][0] +
                                 (wm * 64 + i * 16 + l16) * 128 + cs * 16);
#pragma unroll
      for (int j = 0; j < 4; j++)
        bfr[j] = *(const bf16x8*)((const char*)&Bs[0][0] +
                                  (wn * 32 + (j & 1) * 16 + (j >> 1) * 64 + l16) * 128 + cs * 16);
#pragma unroll
      for (int i = 0; i < 4; i++)
#pragma unroll
        for (int j = 0; j < 4; j++)
          acc[i][j] = __builtin_amdgcn_mfma_f32_16x16x32_bf16(af[i], bfr[j], acc[i][j], 0, 0, 0);
    }
    __syncthreads();
  }

  const int bidx = m0 >> 11;            // batch
  const int lbase = (m0 & 2047) + wm * 64;

  if (hh < 20) {
    // ---- inline RMSNorm row-sums -> Rs (no reg arrays) ----
#pragma unroll
    for (int i = 0; i < 4; i++) {
#pragma unroll
      for (int r = 0; r < 4; r++) {
        float s2 = acc[i][0][r] * acc[i][0][r] + acc[i][1][r] * acc[i][1][r] +
                   acc[i][2][r] * acc[i][2][r] + acc[i][3][r] * acc[i][3][r];
#pragma unroll
        for (int m = 1; m < 16; m <<= 1) s2 += __shfl_xor(s2, m, 64);
        if (l16 == 0) Rs[wm][wn][i * 16 + quad * 4 + r] = s2;
      }
    }
    __syncthreads();

    const float* wt = hh < 16 ? qw : kw;
    const float qs_ = hh < 16 ? 0.08838834764831845f * 1.4426950408889634f : 1.0f;
    u16* dst; size_t hb;
    if (hh < 16) { dst = qo; hb = (size_t)(bidx * 16 + hh) * 2048 * 128; }
    else         { dst = ko; hb = (size_t)(bidx * 4 + (hh - 16)) * 2048 * 128; }

    const int d0 = wn * 32 + l16;
    const float wt00 = wt[d0],      wt01 = wt[d0 + 64];       // j=0 pair
    const float wt10 = wt[d0 + 16], wt11 = wt[d0 + 80];       // j=1 pair

#pragma unroll
    for (int i = 0; i < 4; i++) {
#pragma unroll
      for (int r = 0; r < 4; r++) {
        int row64 = i * 16 + quad * 4 + r;
        float inv = rsqrtf((Rs[wm][0][row64] + Rs[wm][1][row64]) * (1.0f / 128.0f) + 1e-6f);
        int l = lbase + i * 16 + quad * 4 + r;
        const float* cl = cosT + l * 128;
        const float* sl = sinT + l * 128;
#pragma unroll
        for (int j = 0; j < 2; ++j) {
          int d = d0 + j * 16;
          float nv0 = acc[i][j][r]     * inv * (j ? wt10 : wt00);
          float nv1 = acc[i][j + 2][r] * inv * (j ? wt11 : wt01);
          float o0 = (nv0 * cl[d]      - nv1 * sl[d])      * qs_;
          float o1 = (nv1 * cl[d + 64] + nv0 * sl[d + 64]) * qs_;
          dst[hb + (size_t)l * 128 + d]      = f2b(o0);
          dst[hb + (size_t)l * 128 + d + 64] = f2b(o1);
        }
      }
    }
  } else {
    // ---- V head: coalesced row store -> vbuf[b][l][kv*128 + col] ----
    const int kv = hh - 20;
    u16* dv = vb + (size_t)bidx * 2048 * 512;
#pragma unroll
    for (int i = 0; i < 4; i++) {
#pragma unroll
      for (int r = 0; r < 4; r++) {
        int gr = lbase + i * 16 + quad * 4 + r;
#pragma unroll
        for (int j = 0; j < 4; j++) {
          int gc = kv * 128 + wn * 32 + (j & 1) * 16 + (j >> 1) * 64 + l16;
          dv[(size_t)gr * 512 + gc] = f2b(acc[i][j][r]);
        }
      }
    }
  }
}

// -------- V transpose: vbuf[b][l][512] -> VT[2,4,128,2048] ----------------
__global__ __launch_bounds__(256) void transpose_v(const u16* __restrict__ vb,
                                                   u16* __restrict__ dst) {
  __shared__ u16 T[64][72];
  const int lt = blockIdx.x, dt = blockIdx.y, bh = blockIdx.z;
  const int b = bh >> 2, kv = bh & 3;
  const u16* s = vb + ((size_t)(b * 2048 + lt * 64)) * 512 + kv * 128 + dt * 64;
  u16*       d = dst + (size_t)bh * 128 * 2048 + (size_t)dt * 64 * 2048 + lt * 64;
  const int t = threadIdx.x;
  const int row = t >> 3, c8 = (t & 7) * 8;
#pragma unroll
  for (int p = 0; p < 2; ++p)
    *(uint4*)&T[p * 32 + row][c8] = *(const uint4*)(s + (size_t)(p * 32 + row) * 512 + c8);
  __syncthreads();
#pragma unroll
  for (int p = 0; p < 2; ++p) {
    int dr = p * 32 + row;
    u16 o[8];
#pragma unroll
    for (int j = 0; j < 8; ++j) o[j] = T[c8 + j][dr];
    *(uint4*)(d + (size_t)dr * 2048 + c8) = *(uint4*)o;
  }
}

// ---------------- bf16 GEMM: C[M,N] = A[M,K] @ B[N,K]^T (fp32 out) --------
__global__ __launch_bounds__(256) void gemm_bt(const u16* __restrict__ A,
                                               const u16* __restrict__ Bm,
                                               float* __restrict__ C,
                                               int M, int N, int K) {
  __shared__ u16 As[128][64];
  __shared__ u16 Bs[128][64];
  const int tid  = threadIdx.x;
  const int w    = tid >> 6, lane = tid & 63, quad = lane >> 4, l16 = lane & 15;
  const int wm   = w >> 1, wn = w & 1;
  const int m0   = blockIdx.y * 128, n0 = blockIdx.x * 128;

  f32x4 zero = {0.f, 0.f, 0.f, 0.f};
  f32x4 acc[4][4];
#pragma unroll
  for (int i = 0; i < 4; i++)
#pragma unroll
    for (int j = 0; j < 4; j++) acc[i][j] = zero;

  const int srow = lane >> 3;
  const int swz8 = ((lane & 7) ^ (lane >> 3)) * 8;

  for (int k0 = 0; k0 < K; k0 += 64) {
#pragma unroll
    for (int p = 0; p < 4; ++p) {
      int row = p * 32 + w * 8 + srow;
      __builtin_amdgcn_global_load_lds(
          (const AS1 void*)(A + (size_t)(m0 + row) * K + k0 + swz8),
          (AS3 void*)((char*)&As[0][0] + p * 4096 + w * 1024), 16, 0, 0);
      __builtin_amdgcn_global_load_lds(
          (const AS1 void*)(Bm + (size_t)(n0 + row) * K + k0 + swz8),
          (AS3 void*)((char*)&Bs[0][0] + p * 4096 + w * 1024), 16, 0, 0);
    }
    __syncthreads();
#pragma unroll
    for (int kk = 0; kk < 64; kk += 32) {
      const int cs = ((kk >> 3) + quad) ^ (l16 & 7);
      bf16x8 af[4], bfr[4];
#pragma unroll
      for (int i = 0; i < 4; i++)
        af[i] = *(const bf16x8*)((const char*)&As[0][0] +
                                 (wm * 64 + i * 16 + l16) * 128 + cs * 16);
#pragma unroll
      for (int j = 0; j < 4; j++)
        bfr[j] = *(const bf16x8*)((const char*)&Bs[0][0] +
                                  (wn * 64 + j * 16 + l16) * 128 + cs * 16);
#pragma unroll
      for (int i = 0; i < 4; i++)
#pragma unroll
        for (int j = 0; j < 4; j++)
          acc[i][j] = __builtin_amdgcn_mfma_f32_16x16x32_bf16(af[i], bfr[j], acc[i][j], 0, 0, 0);
    }
    __syncthreads();
  }

#pragma unroll
  for (int i = 0; i < 4; i++) {
#pragma unroll
    for (int r = 0; r < 4; r++) {
      int gr = m0 + wm * 64 + i * 16 + quad * 4 + r;
#pragma unroll
      for (int j = 0; j < 4; j++) {
        int gc = n0 + wn * 64 + j * 16 + l16;
        C[(size_t)gr * N + gc] = acc[i][j][r];
      }
    }
  }
}

// -------- GQA-merged sliding-window flash attention (S^T dataflow) ---------
// XCD-pinned: flat&7 -> (kvh,b), flat>>3 -> q0 block (64 rows).
// Block: 64 q-rows x 4 heads (one kv-head), 8 waves, 100KB LDS.
// K/V: global_load_lds w=16, pre-swizzled src, XOR-swizzled reads.
// Ps: padded stride 144B, no XOR — conflict-free b64 write / b128 read.
__global__ __launch_bounds__(512) void flash_swa(const u16* __restrict__ Q,
                                                 const u16* __restrict__ Kg,
                                                 const u16* __restrict__ VTg,
                                                 u16* __restrict__ Og) {
  constexpr int L = 2048, D = 128;
  __shared__ u16 Ks[2][64][128];   // 32KB [key][d], chunk c at c^(row&7)
  __shared__ u16 Vt[2][128][64];   // 32KB [d][key], chunk c at c^(row&7)
  __shared__ u16 Ps[8][32][72];    // 36KB per-wave P (32 q-rows), padded

  const int flat = blockIdx.x;         // 256 blocks; hw xcd = flat & 7
  const int kvh  = flat & 3;
  const int b    = (flat >> 2) & 1;
  const int q0   = (flat >> 3) * 64;   // sequential q0 per (kvh,b) per XCD
  const int tid = threadIdx.x;
  const int w = tid >> 6, lane = tid & 63, quad = lane >> 4, l16 = lane & 15;
  const int hd = kvh * 4 + (w >> 1);   // global head
  const int qh = w & 1;                // q-half within the 64-row block

  const u16* Qb  = Q   + (size_t)(b * 16 + hd)  * L * D;
  const u16* Kb  = Kg  + (size_t)(b * 4 + kvh) * L * D;
  const u16* VTb = VTg + (size_t)(b * 4 + kvh) * D * L;

  bf16x8 qf[2][4];
#pragma unroll
  for (int qs = 0; qs < 2; ++qs) {
    int qr = q0 + qh * 32 + qs * 16 + l16;
#pragma unroll
    for (int ks = 0; ks < 4; ++ks)
      qf[qs][ks] = *(const bf16x8*)(Qb + (size_t)qr * D + ks * 32 + quad * 8);
  }
  const int qi0 = q0 + qh * 32 + l16;   // q row of s-lane (qs adds 16)

  int kt0   = q0 > 512 ? q0 - 512 : 0;
  int ktend = q0 + 64 + 512; if (ktend > L) ktend = L;
  const int nt = (ktend - kt0) >> 6;

  const u16* srcK[2];
  const u16* srcV[2];
#pragma unroll
  for (int j = 0; j < 2; ++j) {
    int rk = w * 8 + j * 4 + quad;                 // K row 0..63
    int ck = ((lane & 15) ^ (rk & 7)) * 8;
    srcK[j] = Kb + (size_t)(kt0 + rk) * D + ck;
    int rv = w * 16 + j * 8 + (lane >> 3);         // V row 0..127
    int cv = ((lane & 7) ^ ((lane >> 3) & 7)) * 8;
    srcV[j] = VTb + (size_t)rv * L + kt0 + cv;
  }

#define STAGE(bb) do {                                                        \
    char* kdst = (char*)&Ks[bb][0][0] + w * 2048;                             \
    char* vdst = (char*)&Vt[bb][0][0] + w * 2048;                             \
    _Pragma("unroll")                                                         \
    for (int j = 0; j < 2; ++j) {                                             \
      __builtin_amdgcn_global_load_lds((const AS1 void*)srcK[j],              \
          (AS3 void*)(kdst + j * 1024), 16, 0, 0);                            \
      srcK[j] += 64 * D;                                                      \
    }                                                                         \
    _Pragma("unroll")                                                         \
    for (int j = 0; j < 2; ++j) {                                             \
      __builtin_amdgcn_global_load_lds((const AS1 void*)srcV[j],              \
          (AS3 void*)(vdst + j * 1024), 16, 0, 0);                            \
      srcV[j] += 64;                                                          \
    }                                                                         \
  } while (0)

  f32x4 zero = {0.f, 0.f, 0.f, 0.f};
  f32x4 o[2][8];
#pragma unroll
  for (int qs = 0; qs < 2; ++qs)
#pragma unroll
    for (int i = 0; i < 8; i++) o[qs][i] = zero;
  float lrow[2] = {0.f, 0.f};

  STAGE(0);
  __syncthreads();          // drains vmcnt(0): tile 0 resident
  int cur = 0;

  for (int t = 0; t < nt; ++t) {
    const int kt = kt0 + t * 64;
    if (t + 1 < nt) STAGE(cur ^ 1);   // async prefetch under this tile's compute

    const char* kbase = (const char*)&Ks[cur][0][0];
    const char* vbase = (const char*)&Vt[cur][0][0];

    // ---- S^T = K x Q^T : s[qs][ct], K-frag reused across both q-subs ----
    f32x4 s[2][4];
#pragma unroll
    for (int qs = 0; qs < 2; ++qs)
#pragma unroll
      for (int ct = 0; ct < 4; ct++) s[qs][ct] = zero;
    __builtin_amdgcn_s_setprio(1);
#pragma unroll
    for (int ks = 0; ks < 4; ++ks) {
#pragma unroll
      for (int ct = 0; ct < 4; ++ct) {
        bf16x8 kf = *(const bf16x8*)(kbase + (ct * 16 + l16) * 256 +
                                     (((ks * 4 + quad) ^ (l16 & 7)) * 16));
        s[0][ct] = __builtin_amdgcn_mfma_f32_16x16x32_bf16(kf, qf[0][ks], s[0][ct], 0, 0, 0);
        s[1][ct] = __builtin_amdgcn_mfma_f32_16x16x32_bf16(kf, qf[1][ks], s[1][ct], 0, 0, 0);
      }
    }
    __builtin_amdgcn_s_setprio(0);

    // ---- P = exp2(S^T) (no max-sub), in-lane psum, pack to Ps[q][k] ----
    bool need_mask = (kt + 448 < q0) || (kt > q0 + 448);
#pragma unroll
    for (int qs = 0; qs < 2; ++qs) {
      float psum = 0.f;
      u16* psw = &Ps[w][qs * 16 + l16][0];
#pragma unroll
      for (int ct = 0; ct < 4; ct++) {
        u16 ph[4];
#pragma unroll
        for (int r = 0; r < 4; r++) {
          float x = s[qs][ct][r];
          if (need_mask) {
            int ki = kt + ct * 16 + quad * 4 + r;
            int dd = (qi0 + qs * 16) - ki; if (dd < 0) dd = -dd;
            if (dd > 512) x = -__builtin_inff();
          }
          float p = exp2f(x);
          psum += p;
          ph[r] = f2b(p);
        }
        uint2 pk;
        pk.x = (u32)ph[0] | ((u32)ph[1] << 16);
        pk.y = (u32)ph[2] | ((u32)ph[3] << 16);
        *(uint2*)(psw + ct * 16 + quad * 4) = pk;
      }
      psum += __shfl_xor(psum, 16, 64);
      psum += __shfl_xor(psum, 32, 64);
      lrow[qs] += psum;
    }

    // ---- O += P V  (P as A-operand, V-frag reused across both q-subs) ----
    bf16x8 pf[2][2];
#pragma unroll
    for (int qs = 0; qs < 2; ++qs) {
#pragma unroll
      for (int ks2 = 0; ks2 < 2; ++ks2)
        pf[qs][ks2] = *(const bf16x8*)(&Ps[w][qs * 16 + l16][ks2 * 32 + quad * 8]);
    }
    __builtin_amdgcn_s_setprio(1);
#pragma unroll
    for (int dt = 0; dt < 8; ++dt) {
#pragma unroll
      for (int ks2 = 0; ks2 < 2; ++ks2) {
        bf16x8 vf = *(const bf16x8*)(vbase + (dt * 16 + l16) * 128 +
                                     (((ks2 * 4 + quad) ^ (l16 & 7)) * 16));
        o[0][dt] = __builtin_amdgcn_mfma_f32_16x16x32_bf16(pf[0][ks2], vf, o[0][dt], 0, 0, 0);
        o[1][dt] = __builtin_amdgcn_mfma_f32_16x16x32_bf16(pf[1][ks2], vf, o[1][dt], 0, 0, 0);
      }
    }
    __builtin_amdgcn_s_setprio(0);

    __syncthreads();   // vmcnt(0): prefetch done; all waves done reading cur
    cur ^= 1;
  }
#undef STAGE

  // ---- epilogue: fetch lrow for this lane's output rows, store ----
#pragma unroll
  for (int qs = 0; qs < 2; ++qs) {
#pragma unroll
    for (int r = 0; r < 4; r++) {
      float lv  = __shfl(lrow[qs], (lane & 48) + quad * 4 + r, 64);
      float inv = 1.0f / lv;
      int qr = q0 + qh * 32 + qs * 16 + quad * 4 + r;
      size_t base = ((size_t)(b * L + qr)) * 2048 + hd * 128;
#pragma unroll
      for (int dt = 0; dt < 8; dt++)
        Og[base + dt * 16 + l16] = f2b(o[qs][dt][r] * inv);
    }
  }
}

// ---------------- launch ----------------
extern "C" void kernel_launch(void* const* d_in, const int* in_sizes, int n_in,
                              void* d_out, int out_size, void* d_ws, size_t ws_size,
                              hipStream_t stream) {
  const float* x    = (const float*)d_in[0];
  const float* cosT = (const float*)d_in[1];
  const float* sinT = (const float*)d_in[2];
  const float* Wq   = (const float*)d_in[3];
  const float* Wk   = (const float*)d_in[4];
  const float* Wv   = (const float*)d_in[5];
  const float* Wo   = (const float*)d_in[6];
  const float* qw   = (const float*)d_in[7];
  const float* kw   = (const float*)d_in[8];

  char* ws = (char*)d_ws;
  u16* x_bf    = (u16*)(ws + 0);          // 16 MB  [4096,2048]
  u16* wqkv_bf = (u16*)(ws + 16777216);   // 12 MB  [3072,2048]
  u16* wo_bf   = (u16*)(ws + 29360128);   //  8 MB  [2048,2048]
  u16* vbuf    = (u16*)(ws + 37748736);   //  4 MB  [2,2048,512]  (v rows)
  u16* vt_bf   = (u16*)(ws + 41943040);   //  4 MB  [2,4,128,2048]
  u16* q_bf    = (u16*)(ws + 62914560);   // 16 MB  [2,16,2048,128]
  u16* k_bf    = (u16*)(ws + 79691776);   //  4 MB  [2,4,2048,128]
  u16* attn_bf = x_bf;                    // 16 MB  [4096,2048]    (reuses x)

  cvt_all<<<18432, 256, 0, stream>>>(x, Wq, Wk, Wv, Wo, x_bf, wqkv_bf, wo_bf);
  gemm_qkv<<<dim3(24, 32), 256, 0, stream>>>(x_bf, wqkv_bf, cosT, sinT, qw, kw,
                                             q_bf, k_bf, vbuf);
  transpose_v<<<dim3(32, 2, 8), 256, 0, stream>>>(vbuf, vt_bf);
  flash_swa<<<dim3(256, 1, 1), 512, 0, stream>>>(q_bf, k_bf, vt_bf, attn_bf);
  gemm_bt<<<dim3(16, 32), 256, 0, stream>>>(attn_bf, wo_bf, (float*)d_out,
                                            4096, 2048, 2048);
}

// Round 17
// 293.164 us; speedup vs baseline: 1.0655x; 1.0655x over previous
//
#include <hip/hip_runtime.h>
#include <hip/hip_bf16.h>

// B=2, L=2048, hidden=2048, H=16, KV=4, D=128, WIN=512
// Pipeline (5 dispatches) — reverted to R9/R10 best-known structure:
//   1) fused cast x, Wq|Wk|Wv, Wo -> bf16
//   2) qkv = x @ Wqkv^T   (plain MFMA GEMM, 811 TF measured)
//   3) rmsrope_tv: RMSNorm(q,k)+RoPE scatter + V transpose (merged)
//      (RoPE tables have cos[l][d]==cos[l][d+64] -> half the table loads)
//   4) sliding-window flash attention (GQA-merged 64-row, XCD-pinned,
//      S^T dataflow, padded Ps)
//   5) out = attn @ Wo^T (fp32 out)
// NOTE: gemm-epilogue fusion of (3) was measured at +33us vs +13us separate
// (R14/R16: cos/sin table loads + post-K-loop serialization) — do not refuse.

typedef unsigned short u16;
typedef unsigned int u32;
typedef __attribute__((ext_vector_type(8))) short bf16x8;
typedef __attribute__((ext_vector_type(4))) float f32x4;

#define AS1 __attribute__((address_space(1)))
#define AS3 __attribute__((address_space(3)))

__device__ __forceinline__ u16 f2b(float f) {
  union { float f; u32 u; } c; c.f = f;
  return (u16)((c.u + 0x8000u) >> 16);   // fast round; inputs bounded, no NaN/inf
}
__device__ __forceinline__ float b2f(u16 u) {
  union { u32 u; float f; } c; c.u = ((u32)u) << 16; return c.f;
}

// ---------------- fused fp32 -> bf16 casts ----------------
__global__ __launch_bounds__(256) void cvt_all(const float* __restrict__ x,
                                               const float* __restrict__ wq,
                                               const float* __restrict__ wk,
                                               const float* __restrict__ wv,
                                               const float* __restrict__ wo,
                                               u16* __restrict__ xb,
                                               u16* __restrict__ wqkvb,
                                               u16* __restrict__ wob) {
  int blk = blockIdx.x;
  const float* s; u16* d; int off;
  if (blk < 8192)       { s = x;  d = xb;              off = blk * 1024; }
  else if (blk < 12288) { s = wq; d = wqkvb;           off = (blk - 8192) * 1024; }
  else if (blk < 13312) { s = wk; d = wqkvb + 4194304; off = (blk - 12288) * 1024; }
  else if (blk < 14336) { s = wv; d = wqkvb + 5242880; off = (blk - 13312) * 1024; }
  else                  { s = wo; d = wob;             off = (blk - 14336) * 1024; }
  int i = off + threadIdx.x * 4;
  float4 v = *(const float4*)(s + i);
  ushort4 o;
  o.x = f2b(v.x); o.y = f2b(v.y); o.z = f2b(v.z); o.w = f2b(v.w);
  *(ushort4*)(d + i) = o;
}

// ---------------- bf16 GEMM: C[M,N] = A[M,K] @ B[N,K]^T --------------------
// 128x128 tile, BK=64, 4 waves (2x2), 4x4 16x16x32 MFMAs per wave.
// global_load_lds width=16 into XOR-swizzled [128][64] LDS.
template<int F32OUT>
__global__ __launch_bounds__(256) void gemm_bt(const u16* __restrict__ A,
                                               const u16* __restrict__ Bm,
                                               void* __restrict__ C,
                                               int M, int N, int K) {
  __shared__ u16 As[128][64];
  __shared__ u16 Bs[128][64];
  const int tid  = threadIdx.x;
  const int w    = tid >> 6, lane = tid & 63, quad = lane >> 4, l16 = lane & 15;
  const int wm   = w >> 1, wn = w & 1;
  const int m0   = blockIdx.y * 128, n0 = blockIdx.x * 128;

  f32x4 zero = {0.f, 0.f, 0.f, 0.f};
  f32x4 acc[4][4];
#pragma unroll
  for (int i = 0; i < 4; i++)
#pragma unroll
    for (int j = 0; j < 4; j++) acc[i][j] = zero;

  const int srow = lane >> 3;
  const int swz8 = ((lane & 7) ^ (lane >> 3)) * 8;

  for (int k0 = 0; k0 < K; k0 += 64) {
#pragma unroll
    for (int p = 0; p < 4; ++p) {
      int row = p * 32 + w * 8 + srow;
      __builtin_amdgcn_global_load_lds(
          (const AS1 void*)(A + (size_t)(m0 + row) * K + k0 + swz8),
          (AS3 void*)((char*)&As[0][0] + p * 4096 + w * 1024), 16, 0, 0);
      __builtin_amdgcn_global_load_lds(
          (const AS1 void*)(Bm + (size_t)(n0 + row) * K + k0 + swz8),
          (AS3 void*)((char*)&Bs[0][0] + p * 4096 + w * 1024), 16, 0, 0);
    }
    __syncthreads();
#pragma unroll
    for (int kk = 0; kk < 64; kk += 32) {
      const int cs = ((kk >> 3) + quad) ^ (l16 & 7);
      bf16x8 af[4], bfr[4];
#pragma unroll
      for (int i = 0; i < 4; i++)
        af[i] = *(const bf16x8*)((const char*)&As[0][0] +
                                 (wm * 64 + i * 16 + l16) * 128 + cs * 16);
#pragma unroll
      for (int j = 0; j < 4; j++)
        bfr[j] = *(const bf16x8*)((const char*)&Bs[0][0] +
                                  (wn * 64 + j * 16 + l16) * 128 + cs * 16);
#pragma unroll
      for (int i = 0; i < 4; i++)
#pragma unroll
        for (int j = 0; j < 4; j++)
          acc[i][j] = __builtin_amdgcn_mfma_f32_16x16x32_bf16(af[i], bfr[j], acc[i][j], 0, 0, 0);
    }
    __syncthreads();
  }

#pragma unroll
  for (int i = 0; i < 4; i++) {
#pragma unroll
    for (int r = 0; r < 4; r++) {
      int gr = m0 + wm * 64 + i * 16 + quad * 4 + r;
#pragma unroll
      for (int j = 0; j < 4; j++) {
        int gc = n0 + wn * 64 + j * 16 + l16;
        if (F32OUT) ((float*)C)[(size_t)gr * N + gc] = acc[i][j][r];
        else        ((u16*)C)[(size_t)gr * N + gc]   = f2b(acc[i][j][r]);
      }
    }
  }
}

// ---- merged: RMSNorm+RoPE scatter (q,k)  +  V transpose -> VT ------------
// blocks [0,20480): rmsrope; blocks [20480,20992): transpose_v
// RoPE table symmetry: cosT[l][d] == cosT[l][d+64] (emb = concat(freqs,freqs))
__global__ __launch_bounds__(256) void rmsrope_tv(const u16* __restrict__ qkv,
                                                  const float* __restrict__ cosT,
                                                  const float* __restrict__ sinT,
                                                  const float* __restrict__ qw,
                                                  const float* __restrict__ kw,
                                                  u16* __restrict__ qo,
                                                  u16* __restrict__ ko,
                                                  u16* __restrict__ vt) {
  __shared__ u16 T[64][72];
  if (blockIdx.x < 20480) {
    int wid  = blockIdx.x * 4 + (threadIdx.x >> 6);
    int lane = threadIdx.x & 63;
    int r  = wid / 20;
    int hh = wid % 20;
    int b = r >> 11, l = r & 2047;
    int cb = hh < 16 ? hh * 128 : 2048 + (hh - 16) * 128;
    const u16* src = qkv + (size_t)r * 3072 + cb;
    float v0 = b2f(src[lane]);
    float v1 = b2f(src[lane + 64]);
    float ss = v0 * v0 + v1 * v1;
#pragma unroll
    for (int off = 1; off < 64; off <<= 1) ss += __shfl_xor(ss, off, 64);
    float inv = rsqrtf(ss * (1.0f / 128.0f) + 1e-6f);
    const float* wt = hh < 16 ? qw : kw;
    float n0 = v0 * inv * wt[lane];
    float n1 = v1 * inv * wt[lane + 64];
    float c0 = cosT[l * 128 + lane];      // == cosT[l*128+64+lane]
    float s0 = sinT[l * 128 + lane];      // == sinT[l*128+64+lane]
    float o0 = n0 * c0 - n1 * s0;
    float o1 = n1 * c0 + n0 * s0;
    const float qscale = 0.08838834764831845f * 1.4426950408889634f; // 1/sqrt(D)*log2e
    u16* dst; size_t base;
    if (hh < 16) { dst = qo; base = ((size_t)(b * 16 + hh) * 2048 + l) * 128;
                   o0 *= qscale; o1 *= qscale; }
    else         { dst = ko; base = ((size_t)(b * 4 + (hh - 16)) * 2048 + l) * 128; }
    dst[base + lane]      = f2b(o0);
    dst[base + 64 + lane] = f2b(o1);
  } else {
    int bid = blockIdx.x - 20480;             // 512 blocks
    const int lt = bid & 31, dt = (bid >> 5) & 1, bh = bid >> 6;
    const int b = bh >> 2, kv = bh & 3;
    const u16* s = qkv + ((size_t)(b * 2048 + lt * 64)) * 3072 + 2560 + kv * 128 + dt * 64;
    u16*       d = vt + (size_t)bh * 128 * 2048 + (size_t)dt * 64 * 2048 + lt * 64;
    const int t = threadIdx.x;
    const int row = t >> 3, c8 = (t & 7) * 8;
#pragma unroll
    for (int p = 0; p < 2; ++p)
      *(uint4*)&T[p * 32 + row][c8] = *(const uint4*)(s + (size_t)(p * 32 + row) * 3072 + c8);
    __syncthreads();
#pragma unroll
    for (int p = 0; p < 2; ++p) {
      int dr = p * 32 + row;
      u16 o[8];
#pragma unroll
      for (int j = 0; j < 8; ++j) o[j] = T[c8 + j][dr];
      *(uint4*)(d + (size_t)dr * 2048 + c8) = *(uint4*)o;
    }
  }
}

// -------- GQA-merged sliding-window flash attention (S^T dataflow) ---------
// XCD-pinned: flat&7 -> (kvh,b), flat>>3 -> q0 block (64 rows).
// Block: 64 q-rows x 4 heads (one kv-head), 8 waves, 100KB LDS.
// K/V: global_load_lds w=16, pre-swizzled src, XOR-swizzled reads.
// Ps: padded stride 144B, no XOR — conflict-free b64 write / b128 read.
__global__ __launch_bounds__(512) void flash_swa(const u16* __restrict__ Q,
                                                 const u16* __restrict__ Kg,
                                                 const u16* __restrict__ VTg,
                                                 u16* __restrict__ Og) {
  constexpr int L = 2048, D = 128;
  __shared__ u16 Ks[2][64][128];   // 32KB [key][d], chunk c at c^(row&7)
  __shared__ u16 Vt[2][128][64];   // 32KB [d][key], chunk c at c^(row&7)
  __shared__ u16 Ps[8][32][72];    // 36KB per-wave P (32 q-rows), padded

  const int flat = blockIdx.x;         // 256 blocks; hw xcd = flat & 7
  const int kvh  = flat & 3;
  const int b    = (flat >> 2) & 1;
  const int q0   = (flat >> 3) * 64;   // sequential q0 per (kvh,b) per XCD
  const int tid = threadIdx.x;
  const int w = tid >> 6, lane = tid & 63, quad = lane >> 4, l16 = lane & 15;
  const int hd = kvh * 4 + (w >> 1);   // global head
  const int qh = w & 1;                // q-half within the 64-row block

  const u16* Qb  = Q   + (size_t)(b * 16 + hd)  * L * D;
  const u16* Kb  = Kg  + (size_t)(b * 4 + kvh) * L * D;
  const u16* VTb = VTg + (size_t)(b * 4 + kvh) * D * L;

  bf16x8 qf[2][4];
#pragma unroll
  for (int qs = 0; qs < 2; ++qs) {
    int qr = q0 + qh * 32 + qs * 16 + l16;
#pragma unroll
    for (int ks = 0; ks < 4; ++ks)
      qf[qs][ks] = *(const bf16x8*)(Qb + (size_t)qr * D + ks * 32 + quad * 8);
  }
  const int qi0 = q0 + qh * 32 + l16;   // q row of s-lane (qs adds 16)

  int kt0   = q0 > 512 ? q0 - 512 : 0;
  int ktend = q0 + 64 + 512; if (ktend > L) ktend = L;
  const int nt = (ktend - kt0) >> 6;

  const u16* srcK[2];
  const u16* srcV[2];
#pragma unroll
  for (int j = 0; j < 2; ++j) {
    int rk = w * 8 + j * 4 + quad;                 // K row 0..63
    int ck = ((lane & 15) ^ (rk & 7)) * 8;
    srcK[j] = Kb + (size_t)(kt0 + rk) * D + ck;
    int rv = w * 16 + j * 8 + (lane >> 3);         // V row 0..127
    int cv = ((lane & 7) ^ ((lane >> 3) & 7)) * 8;
    srcV[j] = VTb + (size_t)rv * L + kt0 + cv;
  }

#define STAGE(bb) do {                                                        \
    char* kdst = (char*)&Ks[bb][0][0] + w * 2048;                             \
    char* vdst = (char*)&Vt[bb][0][0] + w * 2048;                             \
    _Pragma("unroll")                                                         \
    for (int j = 0; j < 2; ++j) {                                             \
      __builtin_amdgcn_global_load_lds((const AS1 void*)srcK[j],              \
          (AS3 void*)(kdst + j * 1024), 16, 0, 0);                            \
      srcK[j] += 64 * D;                                                      \
    }                                                                         \
    _Pragma("unroll")                                                         \
    for (int j = 0; j < 2; ++j) {                                             \
      __builtin_amdgcn_global_load_lds((const AS1 void*)srcV[j],              \
          (AS3 void*)(vdst + j * 1024), 16, 0, 0);                            \
      srcV[j] += 64;                                                          \
    }                                                                         \
  } while (0)

  f32x4 zero = {0.f, 0.f, 0.f, 0.f};
  f32x4 o[2][8];
#pragma unroll
  for (int qs = 0; qs < 2; ++qs)
#pragma unroll
    for (int i = 0; i < 8; i++) o[qs][i] = zero;
  float lrow[2] = {0.f, 0.f};

  STAGE(0);
  __syncthreads();          // drains vmcnt(0): tile 0 resident
  int cur = 0;

  for (int t = 0; t < nt; ++t) {
    const int kt = kt0 + t * 64;
    if (t + 1 < nt) STAGE(cur ^ 1);   // async prefetch under this tile's compute

    const char* kbase = (const char*)&Ks[cur][0][0];
    const char* vbase = (const char*)&Vt[cur][0][0];

    // ---- S^T = K x Q^T : s[qs][ct], K-frag reused across both q-subs ----
    f32x4 s[2][4];
#pragma unroll
    for (int qs = 0; qs < 2; ++qs)
#pragma unroll
      for (int ct = 0; ct < 4; ct++) s[qs][ct] = zero;
    __builtin_amdgcn_s_setprio(1);
#pragma unroll
    for (int ks = 0; ks < 4; ++ks) {
#pragma unroll
      for (int ct = 0; ct < 4; ++ct) {
        bf16x8 kf = *(const bf16x8*)(kbase + (ct * 16 + l16) * 256 +
                                     (((ks * 4 + quad) ^ (l16 & 7)) * 16));
        s[0][ct] = __builtin_amdgcn_mfma_f32_16x16x32_bf16(kf, qf[0][ks], s[0][ct], 0, 0, 0);
        s[1][ct] = __builtin_amdgcn_mfma_f32_16x16x32_bf16(kf, qf[1][ks], s[1][ct], 0, 0, 0);
      }
    }
    __builtin_amdgcn_s_setprio(0);

    // ---- P = exp2(S^T) (no max-sub), in-lane psum, pack to Ps[q][k] ----
    bool need_mask = (kt + 448 < q0) || (kt > q0 + 448);
#pragma unroll
    for (int qs = 0; qs < 2; ++qs) {
      float psum = 0.f;
      u16* psw = &Ps[w][qs * 16 + l16][0];
#pragma unroll
      for (int ct = 0; ct < 4; ct++) {
        u16 ph[4];
#pragma unroll
        for (int r = 0; r < 4; r++) {
          float x = s[qs][ct][r];
          if (need_mask) {
            int ki = kt + ct * 16 + quad * 4 + r;
            int dd = (qi0 + qs * 16) - ki; if (dd < 0) dd = -dd;
            if (dd > 512) x = -__builtin_inff();
          }
          float p = exp2f(x);
          psum += p;
          ph[r] = f2b(p);
        }
        uint2 pk;
        pk.x = (u32)ph[0] | ((u32)ph[1] << 16);
        pk.y = (u32)ph[2] | ((u32)ph[3] << 16);
        *(uint2*)(psw + ct * 16 + quad * 4) = pk;
      }
      psum += __shfl_xor(psum, 16, 64);
      psum += __shfl_xor(psum, 32, 64);
      lrow[qs] += psum;
    }

    // ---- O += P V  (P as A-operand, V-frag reused across both q-subs) ----
    bf16x8 pf[2][2];
#pragma unroll
    for (int qs = 0; qs < 2; ++qs) {
#pragma unroll
      for (int ks2 = 0; ks2 < 2; ++ks2)
        pf[qs][ks2] = *(const bf16x8*)(&Ps[w][qs * 16 + l16][ks2 * 32 + quad * 8]);
    }
    __builtin_amdgcn_s_setprio(1);
#pragma unroll
    for (int dt = 0; dt < 8; ++dt) {
#pragma unroll
      for (int ks2 = 0; ks2 < 2; ++ks2) {
        bf16x8 vf = *(const bf16x8*)(vbase + (dt * 16 + l16) * 128 +
                                     (((ks2 * 4 + quad) ^ (l16 & 7)) * 16));
        o[0][dt] = __builtin_amdgcn_mfma_f32_16x16x32_bf16(pf[0][ks2], vf, o[0][dt], 0, 0, 0);
        o[1][dt] = __builtin_amdgcn_mfma_f32_16x16x32_bf16(pf[1][ks2], vf, o[1][dt], 0, 0, 0);
      }
    }
    __builtin_amdgcn_s_setprio(0);

    __syncthreads();   // vmcnt(0): prefetch done; all waves done reading cur
    cur ^= 1;
  }
#undef STAGE

  // ---- epilogue: fetch lrow for this lane's output rows, store ----
#pragma unroll
  for (int qs = 0; qs < 2; ++qs) {
#pragma unroll
    for (int r = 0; r < 4; r++) {
      float lv  = __shfl(lrow[qs], (lane & 48) + quad * 4 + r, 64);
      float inv = 1.0f / lv;
      int qr = q0 + qh * 32 + qs * 16 + quad * 4 + r;
      size_t base = ((size_t)(b * L + qr)) * 2048 + hd * 128;
#pragma unroll
      for (int dt = 0; dt < 8; dt++)
        Og[base + dt * 16 + l16] = f2b(o[qs][dt][r] * inv);
    }
  }
}

// ---------------- launch ----------------
extern "C" void kernel_launch(void* const* d_in, const int* in_sizes, int n_in,
                              void* d_out, int out_size, void* d_ws, size_t ws_size,
                              hipStream_t stream) {
  const float* x    = (const float*)d_in[0];
  const float* cosT = (const float*)d_in[1];
  const float* sinT = (const float*)d_in[2];
  const float* Wq   = (const float*)d_in[3];
  const float* Wk   = (const float*)d_in[4];
  const float* Wv   = (const float*)d_in[5];
  const float* Wo   = (const float*)d_in[6];
  const float* qw   = (const float*)d_in[7];
  const float* kw   = (const float*)d_in[8];

  char* ws = (char*)d_ws;
  u16* x_bf    = (u16*)(ws + 0);          // 16 MB  [4096,2048]
  u16* wqkv_bf = (u16*)(ws + 16777216);   // 12 MB  [3072,2048]
  u16* wo_bf   = (u16*)(ws + 29360128);   //  8 MB  [2048,2048]
  u16* qkv_bf  = (u16*)(ws + 37748736);   // 24 MB  [4096,3072]
  u16* q_bf    = (u16*)(ws + 62914560);   // 16 MB  [2,16,2048,128]
  u16* k_bf    = (u16*)(ws + 79691776);   //  4 MB  [2,4,2048,128]
  u16* vt_bf   = wqkv_bf;                 //  4 MB  [2,4,128,2048] (reuses wqkv)
  u16* attn_bf = x_bf;                    // 16 MB  [4096,2048]    (reuses x)

  cvt_all<<<18432, 256, 0, stream>>>(x, Wq, Wk, Wv, Wo, x_bf, wqkv_bf, wo_bf);
  gemm_bt<0><<<dim3(24, 32), 256, 0, stream>>>(x_bf, wqkv_bf, qkv_bf, 4096, 3072, 2048);
  rmsrope_tv<<<20992, 256, 0, stream>>>(qkv_bf, cosT, sinT, qw, kw, q_bf, k_bf, vt_bf);
  flash_swa<<<dim3(256, 1, 1), 512, 0, stream>>>(q_bf, k_bf, vt_bf, attn_bf);
  gemm_bt<1><<<dim3(16, 32), 256, 0, stream>>>(attn_bf, wo_bf, d_out, 4096, 2048, 2048);
}